// Round 1
// baseline (343.564 us; speedup 1.0000x reference)
//
#include <hip/hip_runtime.h>

// Problem constants (from reference): B=8, H=W=1024, V=35709, T=70789
#define BATCH 8
#define HWPIX (1024 * 1024)          // H*W = 2^20
#define NVERT 35709

// One thread handles 4 horizontally-adjacent pixels.
// Streamed I/O is fully 16B-vectorized; gathers (triangles 0.85MB,
// diffuse_colors 428KB/batch) are L2-resident.
__global__ __launch_bounds__(256) void raster_kernel(
    const int*   __restrict__ tids,    // [B,H,W] int32
    const float* __restrict__ bary,    // [B,H,W,3] f32
    const float* __restrict__ colors,  // [B,V,3] f32
    const int*   __restrict__ tris,    // [T,3] int32
    float*       __restrict__ out)     // images [B,3,H,W] then alphas [B,1,H,W]
{
    const long long q  = (long long)blockIdx.x * blockDim.x + threadIdx.x; // quad index
    const long long p0 = q << 2;                      // first pixel of the quad
    const int b  = (int)(p0 >> 20);                   // p0 / (H*W)
    const int hw = (int)(p0 & (HWPIX - 1));           // p0 % (H*W)

    // 4 pixels' triangle ids: one int4
    const int4 t4 = ((const int4*)tids)[q];

    // 4 pixels' barycentrics (12 floats): three float4
    const float4 bv0 = ((const float4*)bary)[q * 3 + 0];
    const float4 bv1 = ((const float4*)bary)[q * 3 + 1];
    const float4 bv2 = ((const float4*)bary)[q * 3 + 2];

    const float w0[4] = {bv0.x, bv0.w, bv1.z, bv2.y};
    const float w1[4] = {bv0.y, bv1.x, bv1.w, bv2.z};
    const float w2[4] = {bv0.z, bv1.y, bv2.x, bv2.w};
    const int   tid[4] = {t4.x, t4.y, t4.z, t4.w};

    const float* __restrict__ cb = colors + (long long)b * (3 * NVERT);

    float r[4], g[4], bl[4], a[4];
#pragma unroll
    for (int i = 0; i < 4; ++i) {
        const int t  = tid[i];
        const int v0 = tris[3 * t + 0];
        const int v1 = tris[3 * t + 1];
        const int v2 = tris[3 * t + 2];
        const float* c0 = cb + 3 * v0;
        const float* c1 = cb + 3 * v1;
        const float* c2 = cb + 3 * v2;
        const float u0 = w0[i], u1 = w1[i], u2 = w2[i];
        r[i]  = fminf(fmaxf(c0[0] * u0 + c1[0] * u1 + c2[0] * u2, 0.0f), 1.0f);
        g[i]  = fminf(fmaxf(c0[1] * u0 + c1[1] * u1 + c2[1] * u2, 0.0f), 1.0f);
        bl[i] = fminf(fmaxf(c0[2] * u0 + c1[2] * u1 + c2[2] * u2, 0.0f), 1.0f);
        a[i]  = fminf(fmaxf(2.0f * u0 + 2.0f * u1 + 2.0f * u2, 0.0f), 1.0f);
    }

    // images: [B,3,H,W] channel-planar; hw is a multiple of 4 -> aligned float4
    float* img = out + (long long)b * (3 * HWPIX) + hw;
    ((float4*)(img            ))[0] = make_float4(r[0],  r[1],  r[2],  r[3]);
    ((float4*)(img +     HWPIX))[0] = make_float4(g[0],  g[1],  g[2],  g[3]);
    ((float4*)(img + 2 * HWPIX))[0] = make_float4(bl[0], bl[1], bl[2], bl[3]);

    // alphas: [B,1,H,W], appended after images in flat d_out
    float* al = out + (long long)BATCH * 3 * HWPIX + (long long)b * HWPIX + hw;
    ((float4*)al)[0] = make_float4(a[0], a[1], a[2], a[3]);
}

extern "C" void kernel_launch(void* const* d_in, const int* in_sizes, int n_in,
                              void* d_out, int out_size, void* d_ws, size_t ws_size,
                              hipStream_t stream) {
    const int*   tids   = (const int*)  d_in[0];  // px_triangle_ids [B,H,W]
    const float* bary   = (const float*)d_in[1];  // px_barycentric_coords [B,H,W,3]
    const float* colors = (const float*)d_in[2];  // diffuse_colors [B,V,3]
    const int*   tris   = (const int*)  d_in[3];  // triangles [T,3]
    float*       out    = (float*)      d_out;    // images ++ alphas, fp32

    const int quads  = (BATCH * HWPIX) / 4;       // 2,097,152
    const int block  = 256;
    const int grid   = quads / block;             // 8192
    raster_kernel<<<grid, block, 0, stream>>>(tids, bary, colors, tris, out);
}